// Round 3
// baseline (24.554 us; speedup 1.0000x reference)
//
#include <hip/hip_runtime.h>

// Problem constants from reference:
//   top_k_index_sort: (B, 1, TOPK) int32, values in [0, T)
//   patch_feat: (B, T, N, C) f32
//   audio_feat: (B, T, C) f32
// Outputs (concat flat): out_patch (B, TOPK, N, C) then out_audio (B, TOPK, C)
#define B_    16
#define T_    64
#define N_    196
#define C_    512
#define TOPK_ 10

// Per-(b,k) float4 chunk sizes
#define PATCH4 (N_ * C_ / 4)   // 25088
#define AUD4   (C_ / 4)        // 128

#define PATCH_TOTAL4 (B_ * TOPK_ * PATCH4)              // 4,014,080
#define TOTAL4       (PATCH_TOTAL4 + B_ * TOPK_ * AUD4) // 4,034,560

// Native clang vector (HIP's float4 is a class; nontemporal builtin rejects it)
typedef float v4f __attribute__((ext_vector_type(4)));

__global__ void __launch_bounds__(256)
TopKSegsSelection_gather(const int* __restrict__ idx,
                         const v4f* __restrict__ patch,
                         const v4f* __restrict__ audio,
                         v4f* __restrict__ out) {
    const int stride = gridDim.x * blockDim.x;
    for (int i = blockIdx.x * blockDim.x + threadIdx.x; i < TOTAL4; i += stride) {
        v4f v;
        if (i < PATCH_TOTAL4) {
            int bk  = i / PATCH4;             // (b*TOPK + k), magic-mul
            int rem = i - bk * PATCH4;
            int b   = bk / TOPK_;
            int t   = idx[bk];                // top_k_index_sort[b,0,k]
            v = patch[(size_t)(b * T_ + t) * PATCH4 + rem];
        } else {
            int j   = i - PATCH_TOTAL4;
            int bk  = j / AUD4;
            int rem = j - bk * AUD4;
            int b   = bk / TOPK_;
            int t   = idx[bk];
            v = audio[(size_t)(b * T_ + t) * AUD4 + rem];
        }
        // Output is write-once, never re-read: bypass L2 so gathered rows
        // (possible duplicate t within a batch) stay resident for re-hits.
        __builtin_nontemporal_store(v, &out[i]);
    }
}

extern "C" void kernel_launch(void* const* d_in, const int* in_sizes, int n_in,
                              void* d_out, int out_size, void* d_ws, size_t ws_size,
                              hipStream_t stream) {
    const int* idx   = (const int*)d_in[0];
    const v4f* patch = (const v4f*)d_in[1];
    const v4f* audio = (const v4f*)d_in[2];
    v4f*       out   = (v4f*)d_out;

    // Memory-bound: cap grid and grid-stride (~8 iters/thread) to amortize
    // wave setup; 2048 blocks = 256 CUs x 8 blocks.
    const int block = 256;
    const int grid  = 2048;

    TopKSegsSelection_gather<<<grid, block, 0, stream>>>(idx, patch, audio, out);
}

// Round 4
// 24.493 us; speedup vs baseline: 1.0025x; 1.0025x over previous
//
#include <hip/hip_runtime.h>

// Problem constants from reference:
//   top_k_index_sort: (B, 1, TOPK) int32, values in [0, T)
//   patch_feat: (B, T, N, C) f32
//   audio_feat: (B, T, C) f32
// Outputs (concat flat): out_patch (B, TOPK, N, C) then out_audio (B, TOPK, C)
#define B_    16
#define T_    64
#define N_    196
#define C_    512
#define TOPK_ 10

// Per-(b,k) 32-byte (8-float) chunk counts
#define PATCH8 (N_ * C_ / 8)   // 12544
#define AUD8   (C_ / 8)        // 64

#define PATCH_TOTAL8 (B_ * TOPK_ * PATCH8)              // 2,007,040
#define TOTAL8       (PATCH_TOTAL8 + B_ * TOPK_ * AUD8) // 2,017,280

// 32 B per thread: compiles to two global_load_dwordx4 / two store_dwordx4.
typedef float v8f __attribute__((ext_vector_type(8)));

__global__ void __launch_bounds__(256)
TopKSegsSelection_gather(const int* __restrict__ idx,
                         const v8f* __restrict__ patch,
                         const v8f* __restrict__ audio,
                         v8f* __restrict__ out) {
    int i = blockIdx.x * blockDim.x + threadIdx.x;
    if (i >= TOTAL8) return;

    v8f v;
    if (i < PATCH_TOTAL8) {
        int bk  = i / PATCH8;             // (b*TOPK + k), magic-mul
        int rem = i - bk * PATCH8;
        int b   = bk / TOPK_;
        int t   = idx[bk];                // top_k_index_sort[b,0,k]
        v = patch[(size_t)(b * T_ + t) * PATCH8 + rem];
    } else {
        int j   = i - PATCH_TOTAL8;
        int bk  = j / AUD8;
        int rem = j - bk * AUD8;
        int b   = bk / TOPK_;
        int t   = idx[bk];
        v = audio[(size_t)(b * T_ + t) * AUD8 + rem];
    }
    out[i] = v;   // normal store: output fits L3, let it write-allocate
}

extern "C" void kernel_launch(void* const* d_in, const int* in_sizes, int n_in,
                              void* d_out, int out_size, void* d_ws, size_t ws_size,
                              hipStream_t stream) {
    const int* idx   = (const int*)d_in[0];
    const v8f* patch = (const v8f*)d_in[1];
    const v8f* audio = (const v8f*)d_in[2];
    v8f*       out   = (v8f*)d_out;

    const int block = 256;
    const int grid  = (TOTAL8 + block - 1) / block;   // 7880 exactly

    TopKSegsSelection_gather<<<grid, block, 0, stream>>>(idx, patch, audio, out);
}